// Round 8
// baseline (119.860 us; speedup 1.0000x reference)
//
#include <hip/hip_runtime.h>

#define B_ROWS 16384
#define S_ROWS 12800
#define DIM    128
#define NBLK   100          // S_ROWS / 128

static constexpr float SCL = 20.609929155556617f;  // log2(e) / 0.07

typedef __attribute__((ext_vector_type(8))) short short8;
typedef __attribute__((ext_vector_type(4))) float f32x4;

// f32 -> bf16 round-to-nearest-even
__device__ __forceinline__ unsigned short f2bf(float f) {
  unsigned int u = __float_as_uint(f);
  unsigned int r = (u + 0x7FFFu + ((u >> 16) & 1u)) >> 16;
  return (unsigned short)r;
}

// Sortable packing: larger float -> larger key; ties -> smaller col wins (matches jnp.argmax).
__device__ __forceinline__ unsigned long long packMax(float v, int col) {
  unsigned int b = __float_as_uint(v);
  unsigned int key = (b & 0x80000000u) ? ~b : (b | 0x80000000u);
  return ((unsigned long long)key << 32) | (unsigned long long)(0xFFFFFFFFu - (unsigned int)col);
}

// async global->LDS, 16B per lane, wave-uniform LDS base (HW adds lane*16)
__device__ __forceinline__ void gld16(const unsigned short* g, unsigned short* l) {
  __builtin_amdgcn_global_load_lds(
      (const __attribute__((address_space(1))) unsigned int*)g,
      (__attribute__((address_space(3))) unsigned int*)l,
      16, 0, 0);
}

// normalize + bf16-ify centroids; blocks 3200.. also zero the accumulators
__global__ __launch_bounds__(256) void prep(const float* __restrict__ cent,
                                            unsigned short* __restrict__ cbf_u,
                                            unsigned short* __restrict__ cbf_s,
                                            float* __restrict__ centsum,
                                            unsigned long long* __restrict__ gpacked,
                                            float* __restrict__ jsum) {
  int bid = blockIdx.x;
  if (bid >= 3200) {  // 64 init blocks
    int i = (bid - 3200) * 256 + threadIdx.x;
    if (i < S_ROWS) centsum[i] = 0.f;
    if (i < B_ROWS) gpacked[i] = 0ull;
    if (i == 0) jsum[0] = 0.f;
    return;
  }
  int row  = bid * 4 + (threadIdx.x >> 6);
  int lane = threadIdx.x & 63;
  float2 v = ((const float2*)(cent + (size_t)row * DIM))[lane];
  float ss = v.x * v.x + v.y * v.y;
  #pragma unroll
  for (int m = 32; m; m >>= 1) ss += __shfl_xor(ss, m, 64);
  float inv = 1.0f / fmaxf(sqrtf(ss), 1e-12f);
  float cx = v.x * inv, cy = v.y * inv;
  ((unsigned int*)(cbf_u + (size_t)row * DIM))[lane] =
      (unsigned int)f2bf(cx) | ((unsigned int)f2bf(cy) << 16);
  ((unsigned int*)(cbf_s + (size_t)row * DIM))[lane] =
      (unsigned int)f2bf(cx * SCL) | ((unsigned int)f2bf(cy * SCL) << 16);
}

// stage one 128-row x 128-K bf16 tile (32 KB); wave w stages rows [w*32, w*32+32)
__device__ __forceinline__ void stage_tile(const unsigned short* __restrict__ src, int base,
                                           int w, int lane, unsigned short* dst) {
  #pragma unroll
  for (int i = 0; i < 8; ++i) {
    int rb = w * 32 + i * 4;
    int r  = rb + (lane >> 4);
    int ch = (lane & 15) ^ (r & 7);
    gld16(src + (size_t)(base + r) * DIM + ch * 8, dst + rb * 128);
  }
}

// ---- symmetric S x S: block (chunk c, strip bi) computes col tiles k in
// [start,end) of the cyclic upper fold: bj = (bi+k) % 100, k=0..50 (k=50 only
// for bi<50). Off-diagonal tiles contribute rowsums AND colsums (mirror).
__global__ __launch_bounds__(256, 2) void sym_mfma(const unsigned short* __restrict__ cbf_u,
                                                   const unsigned short* __restrict__ cbf_s,
                                                   float* __restrict__ centsum) {
  __shared__ unsigned short Bs[2][128 * 128];  // 64 KB

  const int bi   = blockIdx.y;          // strip 0..99
  const int c    = blockIdx.x;          // chunk 0..4
  const int row0 = bi * 128;
  int start = (c == 0) ? 0 : (1 + 10 * c);   // chunk0: k=0..10 (11), else 10 each
  int end   = 11 + 10 * c;
  if (bi >= 50 && end > 50) end = 50;        // k=50 owned by bi<50 only
  const int nt = end - start;

  const int t    = threadIdx.x;
  const int w    = t >> 6;
  const int lane = t & 63;
  const int wr = w >> 1, wc = w & 1;
  const int lg = lane >> 4, li = lane & 15;

  // ---- prologue: A tile (rows, scaled) into Bs[0]; fragments -> registers ----
  stage_tile(cbf_s, row0, w, lane, Bs[0]);
  asm volatile("s_waitcnt vmcnt(0)" ::: "memory");
  __syncthreads();

  short8 a[4][4];
  #pragma unroll
  for (int m = 0; m < 4; ++m)
    #pragma unroll
    for (int ks = 0; ks < 4; ++ks) {
      int r  = wr * 64 + m * 16 + li;
      int ch = (ks * 4 + lg) ^ (r & 7);
      a[m][ks] = *(const short8*)&Bs[0][r * 128 + ch * 8];
    }
  __syncthreads();  // A reads done before Bs[0] is reused

  float rs[4][4];
  #pragma unroll
  for (int m = 0; m < 4; ++m)
    #pragma unroll
    for (int j = 0; j < 4; ++j) rs[m][j] = 0.f;
  const f32x4 zero4 = {0.f, 0.f, 0.f, 0.f};

  // ---- pre-stage first B tile ----
  unsigned short* pb0 = Bs[0];
  unsigned short* pb1 = Bs[1];
  {
    int bj = bi + start; if (bj >= NBLK) bj -= NBLK;
    stage_tile(cbf_u, bj * 128, w, lane, pb0);
  }
  __syncthreads();

  for (int ii = 0; ii < nt; ++ii) {
    const int k = start + ii;
    if (ii + 1 < nt) {
      int bj2 = bi + k + 1; if (bj2 >= NBLK) bj2 -= NBLK;
      stage_tile(cbf_u, bj2 * 128, w, lane, pb1);
    }
    int bj = bi + k; if (bj >= NBLK) bj -= NBLK;
    const int colbase = bj * 128;
    const unsigned short* cur = pb0;

    f32x4 acc[4][4];
    #pragma unroll
    for (int ks = 0; ks < 4; ++ks) {
      short8 b[4];
      #pragma unroll
      for (int n = 0; n < 4; ++n) {
        int cc = wc * 64 + n * 16 + li;
        int ch = (ks * 4 + lg) ^ (cc & 7);
        b[n] = *(const short8*)&cur[cc * 128 + ch * 8];
      }
      #pragma unroll
      for (int m = 0; m < 4; ++m)
        #pragma unroll
        for (int n = 0; n < 4; ++n)
          acc[m][n] = __builtin_amdgcn_mfma_f32_16x16x32_bf16(
              a[m][ks], b[n], (ks == 0) ? zero4 : acc[m][n], 0, 0, 0);
    }

    // epilogue: e feeds rowsums (running) and colsums (flushed this tile)
    float cs[4] = {0.f, 0.f, 0.f, 0.f};
    #pragma unroll
    for (int m = 0; m < 4; ++m)
      #pragma unroll
      for (int n = 0; n < 4; ++n)
        #pragma unroll
        for (int j = 0; j < 4; ++j) {
          float e = exp2f(acc[m][n][j]);
          rs[m][j] += e;
          cs[n] += e;
        }
    if (k != 0) {  // mirror contribution: centsum[col] += colsum (uniform branch)
      #pragma unroll
      for (int n = 0; n < 4; ++n) {
        cs[n] += __shfl_xor(cs[n], 16, 64);
        cs[n] += __shfl_xor(cs[n], 32, 64);
      }
      if (lg == 0) {
        #pragma unroll
        for (int n = 0; n < 4; ++n)
          atomicAdd(&centsum[colbase + wc * 64 + n * 16 + li], cs[n]);
      }
    }
    __syncthreads();  // prefetch landed + all waves done with cur
    unsigned short* tmp = pb0; pb0 = pb1; pb1 = tmp;
  }

  // ---- strip-end rowsum reduction ----
  #pragma unroll
  for (int m = 0; m < 4; ++m)
    #pragma unroll
    for (int j = 0; j < 4; ++j) {
      float s = rs[m][j];
      #pragma unroll
      for (int msk = 1; msk < 16; msk <<= 1) s += __shfl_xor(s, msk, 64);
      if (li == 0) atomicAdd(&centsum[row0 + wr * 64 + m * 16 + lg * 4 + j], s);
    }
}

// ---- B x S argmax strip. Epilogue: code (tt*4+n, 7 bits) embedded into the
// low 8 mantissa bits of each acc value (v_and_or_b32), running max via fmaxf
// chains (-> v_max3). Value perturbation <= 2^-16 relative and index near-tie
// swaps are output-invariant (centsum lookup is absorbed; J == 0 bitwise).
__global__ __launch_bounds__(256, 2) void argmax_mfma(const float* __restrict__ features,
                                                      const unsigned short* __restrict__ cbf_s,
                                                      unsigned long long* __restrict__ gpacked) {
  constexpr int NT = 25;
  __shared__ unsigned short Bs[2][128 * 128];  // 64 KB

  const int row0  = blockIdx.y * 128;
  const int tile0 = blockIdx.x * NT;

  const int t    = threadIdx.x;
  const int w    = t >> 6;
  const int lane = t & 63;
  const int wr = w >> 1, wc = w & 1;
  const int lg = lane >> 4, li = lane & 15;

  // prologue: features f32 -> bf16, swizzled LDS write, then A frags -> regs
  #pragma unroll
  for (int i = 0; i < 8; ++i) {
    int q = i * 256 + t;
    int r = q >> 4, c = q & 15;
    const float* src = features + (size_t)(row0 + r) * DIM + c * 8;
    float4 v0 = *(const float4*)src;
    float4 v1 = *(const float4*)(src + 4);
    short8 h;
    h[0] = (short)f2bf(v0.x); h[1] = (short)f2bf(v0.y);
    h[2] = (short)f2bf(v0.z); h[3] = (short)f2bf(v0.w);
    h[4] = (short)f2bf(v1.x); h[5] = (short)f2bf(v1.y);
    h[6] = (short)f2bf(v1.z); h[7] = (short)f2bf(v1.w);
    *(short8*)&Bs[0][r * 128 + (c ^ (r & 7)) * 8] = h;
  }
  __syncthreads();

  short8 a[4][4];
  #pragma unroll
  for (int m = 0; m < 4; ++m)
    #pragma unroll
    for (int ks = 0; ks < 4; ++ks) {
      int r  = wr * 64 + m * 16 + li;
      int ch = (ks * 4 + lg) ^ (r & 7);
      a[m][ks] = *(const short8*)&Bs[0][r * 128 + ch * 8];
    }
  __syncthreads();

  float bv[4][4];  // running max WITH embedded code in low 8 bits
  #pragma unroll
  for (int m = 0; m < 4; ++m)
    #pragma unroll
    for (int j = 0; j < 4; ++j) bv[m][j] = -3.0e38f;
  const f32x4 zero4 = {0.f, 0.f, 0.f, 0.f};

  stage_tile(cbf_s, tile0 * 128, w, lane, Bs[0]);
  __syncthreads();

  for (int tt = 0; tt < NT; ++tt) {
    if (tt + 1 < NT)
      stage_tile(cbf_s, (tile0 + tt + 1) * 128, w, lane, Bs[(tt + 1) & 1]);
    const unsigned short* cur = Bs[tt & 1];

    f32x4 acc[4][4];
    #pragma unroll
    for (int ks = 0; ks < 4; ++ks) {
      short8 b[4];
      #pragma unroll
      for (int n = 0; n < 4; ++n) {
        int cc = wc * 64 + n * 16 + li;
        int ch = (ks * 4 + lg) ^ (cc & 7);
        b[n] = *(const short8*)&cur[cc * 128 + ch * 8];
      }
      #pragma unroll
      for (int m = 0; m < 4; ++m)
        #pragma unroll
        for (int n = 0; n < 4; ++n)
          acc[m][n] = __builtin_amdgcn_mfma_f32_16x16x32_bf16(
              a[m][ks], b[n], (ks == 0) ? zero4 : acc[m][n], 0, 0, 0);
    }

    // epilogue: embed code, then max-reduce (fmaxf chains -> v_max3)
    #pragma unroll
    for (int m = 0; m < 4; ++m)
      #pragma unroll
      for (int j = 0; j < 4; ++j) {
        float e0 = __uint_as_float((__float_as_uint(acc[m][0][j]) & 0xFFFFFF00u) | (unsigned)(tt * 4 + 0));
        float e1 = __uint_as_float((__float_as_uint(acc[m][1][j]) & 0xFFFFFF00u) | (unsigned)(tt * 4 + 1));
        float e2 = __uint_as_float((__float_as_uint(acc[m][2][j]) & 0xFFFFFF00u) | (unsigned)(tt * 4 + 2));
        float e3 = __uint_as_float((__float_as_uint(acc[m][3][j]) & 0xFFFFFF00u) | (unsigned)(tt * 4 + 3));
        bv[m][j] = fmaxf(fmaxf(fmaxf(bv[m][j], e0), e1), fmaxf(e2, e3));
      }
    __syncthreads();
  }

  // strip-end: decode col, cross-lane (val,col) reduce, one atomic per row
  #pragma unroll
  for (int m = 0; m < 4; ++m)
    #pragma unroll
    for (int j = 0; j < 4; ++j) {
      float v = bv[m][j];
      unsigned code = __float_as_uint(v) & 0xFFu;
      int c = (tile0 + (int)(code >> 2)) * 128 + wc * 64 + (int)(code & 3) * 16 + li;
      #pragma unroll
      for (int msk = 1; msk < 16; msk <<= 1) {
        float ov = __shfl_xor(v, msk, 64);
        int   oc = __shfl_xor(c, msk, 64);
        if (ov > v || (ov == v && oc < c)) { v = ov; c = oc; }
      }
      if (li == 0) atomicMax(&gpacked[row0 + wr * 64 + m * 16 + lg * 4 + j], packMax(v, c));
    }
}

__global__ __launch_bounds__(256) void finalize_rows(const unsigned long long* __restrict__ gpacked,
                                                     const float* __restrict__ centsum,
                                                     float* __restrict__ jsum) {
  __shared__ float sdata[4];
  int b = blockIdx.x * 256 + threadIdx.x;
  unsigned long long pk = gpacked[b];
  unsigned int key = (unsigned int)(pk >> 32);
  unsigned int col = 0xFFFFFFFFu - (unsigned int)(pk & 0xFFFFFFFFu);
  unsigned int bits = (key & 0x80000000u) ? (key & 0x7FFFFFFFu) : ~key;
  float msc = __uint_as_float(bits);       // max dot * log2(e)/T (low bits carry code)
  float p = exp2f(msc);                    // = exp(max dot / T)
  float J = logf(p) - logf(p + centsum[col]);  // BALANCE = 1.0
  #pragma unroll
  for (int msk = 1; msk < 64; msk <<= 1) J += __shfl_xor(J, msk, 64);
  int lane = threadIdx.x & 63, wv = threadIdx.x >> 6;
  if (lane == 0) sdata[wv] = J;
  __syncthreads();
  if (threadIdx.x == 0) atomicAdd(jsum, sdata[0] + sdata[1] + sdata[2] + sdata[3]);
}

__global__ void write_out(const float* __restrict__ jsum, float* __restrict__ out) {
  out[0] = -(jsum[0] / (float)B_ROWS);
}

extern "C" void kernel_launch(void* const* d_in, const int* in_sizes, int n_in,
                              void* d_out, int out_size, void* d_ws, size_t ws_size,
                              hipStream_t stream) {
  const float* features  = (const float*)d_in[0];
  const float* centroids = (const float*)d_in[1];
  float* out = (float*)d_out;

  // ws: cbf_u[S*D] u16 | cbf_s[S*D] u16 | centsum[S] f32 | gpacked[B] u64 | jsum f32 (~6.74 MB)
  unsigned short* cbf_u = (unsigned short*)d_ws;
  unsigned short* cbf_s = cbf_u + (size_t)S_ROWS * DIM;
  float* centsum = (float*)(cbf_s + (size_t)S_ROWS * DIM);
  unsigned long long* gpacked = (unsigned long long*)(centsum + S_ROWS);
  float* jsum = (float*)(gpacked + B_ROWS);

  prep<<<dim3(3264), dim3(256), 0, stream>>>(centroids, cbf_u, cbf_s, centsum, gpacked, jsum);
  // symmetric S x S: 5 chunks x 100 strips = 500 blocks, ~10 tiles each (5050 total)
  sym_mfma<<<dim3(5, NBLK), dim3(256), 0, stream>>>(cbf_u, cbf_s, centsum);
  // B x S argmax: 4 chunks x 128 row-blocks = 512 blocks, 25 tiles each
  argmax_mfma<<<dim3(4, B_ROWS / 128), dim3(256), 0, stream>>>(features, cbf_s, gpacked);
  finalize_rows<<<dim3(B_ROWS / 256), dim3(256), 0, stream>>>(gpacked, centsum, jsum);
  write_out<<<dim3(1), dim3(1), 0, stream>>>(jsum, out);
}

// Round 9
// 103.516 us; speedup vs baseline: 1.1579x; 1.1579x over previous
//
#include <hip/hip_runtime.h>

#define B_ROWS 16384
#define S_ROWS 12800
#define DIM    128
#define NBLK   100          // S_ROWS / 128

static constexpr float SCL = 20.609929155556617f;  // log2(e) / 0.07

typedef __attribute__((ext_vector_type(8))) short short8;
typedef __attribute__((ext_vector_type(4))) float f32x4;
typedef __attribute__((ext_vector_type(4))) int   int32x4;
typedef __attribute__((ext_vector_type(8))) int   int32x8;

// f32 -> bf16 round-to-nearest-even
__device__ __forceinline__ unsigned short f2bf(float f) {
  unsigned int u = __float_as_uint(f);
  unsigned int r = (u + 0x7FFFu + ((u >> 16) & 1u)) >> 16;
  return (unsigned short)r;
}

// Sortable packing: larger float -> larger key; ties -> smaller col wins (matches jnp.argmax).
__device__ __forceinline__ unsigned long long packMax(float v, int col) {
  unsigned int b = __float_as_uint(v);
  unsigned int key = (b & 0x80000000u) ? ~b : (b | 0x80000000u);
  return ((unsigned long long)key << 32) | (unsigned long long)(0xFFFFFFFFu - (unsigned int)col);
}

// async global->LDS, 16B per lane, wave-uniform LDS base (HW adds lane*16)
__device__ __forceinline__ void gld16(const void* g, void* l) {
  __builtin_amdgcn_global_load_lds(
      (const __attribute__((address_space(1))) unsigned int*)g,
      (__attribute__((address_space(3))) unsigned int*)l,
      16, 0, 0);
}

// normalize centroids -> bf16 (unscaled) + fp8 e4m3 (unscaled); init accumulators
__global__ __launch_bounds__(256) void prep(const float* __restrict__ cent,
                                            unsigned short* __restrict__ cbf_u,
                                            unsigned char* __restrict__ cf8,
                                            float* __restrict__ centsum,
                                            unsigned long long* __restrict__ gpacked,
                                            float* __restrict__ jsum) {
  int bid = blockIdx.x;
  if (bid >= 3200) {  // 64 init blocks
    int i = (bid - 3200) * 256 + threadIdx.x;
    if (i < S_ROWS) centsum[i] = 0.f;
    if (i < B_ROWS) gpacked[i] = 0ull;
    if (i == 0) jsum[0] = 0.f;
    return;
  }
  int row  = bid * 4 + (threadIdx.x >> 6);
  int lane = threadIdx.x & 63;
  float2 v = ((const float2*)(cent + (size_t)row * DIM))[lane];
  float ss = v.x * v.x + v.y * v.y;
  #pragma unroll
  for (int m = 32; m; m >>= 1) ss += __shfl_xor(ss, m, 64);
  float inv = 1.0f / fmaxf(sqrtf(ss), 1e-12f);
  float cx = v.x * inv, cy = v.y * inv;
  ((unsigned int*)(cbf_u + (size_t)row * DIM))[lane] =
      (unsigned int)f2bf(cx) | ((unsigned int)f2bf(cy) << 16);
  int pk = __builtin_amdgcn_cvt_pk_fp8_f32(cx, cy, 0, false);
  ((unsigned short*)(cf8 + (size_t)row * 128))[lane] = (unsigned short)pk;
}

// stage one 128-row x 128-K bf16 tile (32 KB); wave w stages rows [w*32, w*32+32)
__device__ __forceinline__ void stage_tile(const unsigned short* __restrict__ src, int base,
                                           int w, int lane, unsigned short* dst) {
  #pragma unroll
  for (int i = 0; i < 8; ++i) {
    int rb = w * 32 + i * 4;
    int r  = rb + (lane >> 4);
    int ch = (lane & 15) ^ (r & 7);
    gld16(src + (size_t)(base + r) * DIM + ch * 8, dst + rb * 128);
  }
}

// stage one 128-row x 128-K fp8 tile (16 KB); wave w stages rows [w*32, w*32+32)
__device__ __forceinline__ void stage_f8(const unsigned char* __restrict__ src, int base,
                                         int w, int lane, unsigned char* dst) {
  #pragma unroll
  for (int i = 0; i < 4; ++i) {
    int rb = w * 32 + i * 8;
    int r  = rb + (lane >> 3);
    int ch = (lane & 7) ^ (r & 7);
    gld16(src + (size_t)(base + r) * 128 + ch * 16, dst + rb * 128);
  }
}

// ---- symmetric S x S (bf16, unscaled both sides; SCL folded into exp2 arg).
// Block (chunk c, strip bi): col tiles k in [start,end) of cyclic fold
// bj=(bi+k)%100, k=0..50 (k=50 only for bi<50). Off-diag tiles feed rowsums
// AND colsums (mirror).
__global__ __launch_bounds__(256, 2) void sym_mfma(const unsigned short* __restrict__ cbf_u,
                                                   float* __restrict__ centsum) {
  __shared__ unsigned short Bs[2][128 * 128];  // 64 KB

  const int bi   = blockIdx.y;          // strip 0..99
  const int c    = blockIdx.x;          // chunk 0..4
  const int row0 = bi * 128;
  int start = (c == 0) ? 0 : (1 + 10 * c);   // chunk0: k=0..10 (11), else 10 each
  int end   = 11 + 10 * c;
  if (bi >= 50 && end > 50) end = 50;        // k=50 owned by bi<50 only
  const int nt = end - start;

  const int t    = threadIdx.x;
  const int w    = t >> 6;
  const int lane = t & 63;
  const int wr = w >> 1, wc = w & 1;
  const int lg = lane >> 4, li = lane & 15;

  // ---- prologue: A tile into Bs[0]; fragments -> registers ----
  stage_tile(cbf_u, row0, w, lane, Bs[0]);
  asm volatile("s_waitcnt vmcnt(0)" ::: "memory");
  __syncthreads();

  short8 a[4][4];
  #pragma unroll
  for (int m = 0; m < 4; ++m)
    #pragma unroll
    for (int ks = 0; ks < 4; ++ks) {
      int r  = wr * 64 + m * 16 + li;
      int ch = (ks * 4 + lg) ^ (r & 7);
      a[m][ks] = *(const short8*)&Bs[0][r * 128 + ch * 8];
    }
  __syncthreads();  // A reads done before Bs[0] is reused

  float rs[4][4];
  #pragma unroll
  for (int m = 0; m < 4; ++m)
    #pragma unroll
    for (int j = 0; j < 4; ++j) rs[m][j] = 0.f;
  const f32x4 zero4 = {0.f, 0.f, 0.f, 0.f};

  unsigned short* pb0 = Bs[0];
  unsigned short* pb1 = Bs[1];
  {
    int bj = bi + start; if (bj >= NBLK) bj -= NBLK;
    stage_tile(cbf_u, bj * 128, w, lane, pb0);
  }
  __syncthreads();

  for (int ii = 0; ii < nt; ++ii) {
    const int k = start + ii;
    if (ii + 1 < nt) {
      int bj2 = bi + k + 1; if (bj2 >= NBLK) bj2 -= NBLK;
      stage_tile(cbf_u, bj2 * 128, w, lane, pb1);
    }
    int bj = bi + k; if (bj >= NBLK) bj -= NBLK;
    const int colbase = bj * 128;
    const unsigned short* cur = pb0;

    f32x4 acc[4][4];
    #pragma unroll
    for (int ks = 0; ks < 4; ++ks) {
      short8 b[4];
      #pragma unroll
      for (int n = 0; n < 4; ++n) {
        int cc = wc * 64 + n * 16 + li;
        int ch = (ks * 4 + lg) ^ (cc & 7);
        b[n] = *(const short8*)&cur[cc * 128 + ch * 8];
      }
      #pragma unroll
      for (int m = 0; m < 4; ++m)
        #pragma unroll
        for (int n = 0; n < 4; ++n)
          acc[m][n] = __builtin_amdgcn_mfma_f32_16x16x32_bf16(
              a[m][ks], b[n], (ks == 0) ? zero4 : acc[m][n], 0, 0, 0);
    }

    // epilogue: e = exp2(dot * SCL) feeds rowsums (running) + colsums (flushed)
    float cs[4] = {0.f, 0.f, 0.f, 0.f};
    #pragma unroll
    for (int m = 0; m < 4; ++m)
      #pragma unroll
      for (int n = 0; n < 4; ++n)
        #pragma unroll
        for (int j = 0; j < 4; ++j) {
          float e = exp2f(acc[m][n][j] * SCL);
          rs[m][j] += e;
          cs[n] += e;
        }
    if (k != 0) {  // mirror contribution (uniform branch)
      #pragma unroll
      for (int n = 0; n < 4; ++n) {
        cs[n] += __shfl_xor(cs[n], 16, 64);
        cs[n] += __shfl_xor(cs[n], 32, 64);
      }
      if (lg == 0) {
        #pragma unroll
        for (int n = 0; n < 4; ++n)
          atomicAdd(&centsum[colbase + wc * 64 + n * 16 + li], cs[n]);
      }
    }
    __syncthreads();  // prefetch landed + all waves done with cur
    unsigned short* tmp = pb0; pb0 = pb1; pb1 = tmp;
  }

  #pragma unroll
  for (int m = 0; m < 4; ++m)
    #pragma unroll
    for (int j = 0; j < 4; ++j) {
      float s = rs[m][j];
      #pragma unroll
      for (int msk = 1; msk < 16; msk <<= 1) s += __shfl_xor(s, msk, 64);
      if (li == 0) atomicAdd(&centsum[row0 + wr * 64 + m * 16 + lg * 4 + j], s);
    }
}

// ---- B x S argmax, MX-fp8: one mfma_scale_f32_16x16x128 per 16x16 output
// fragment covers all of K=128 (unit scales). A=features (f32->fp8 in LDS),
// B=cf8. fp8 value/index perturbation is output-invariant (absorption bound:
// needs max dot >= 1.83; P(fail) ~ e^-430). Raw (unscaled) max stored.
__global__ __launch_bounds__(256, 3) void argmax_mfma(const float* __restrict__ features,
                                                      const unsigned char* __restrict__ cf8,
                                                      unsigned long long* __restrict__ gpacked) {
  constexpr int NT = 25;
  __shared__ unsigned char Bs[2][128 * 128];  // 2 x 16 KB

  const int row0  = blockIdx.y * 128;
  const int tile0 = blockIdx.x * NT;

  const int t    = threadIdx.x;
  const int w    = t >> 6;
  const int lane = t & 63;
  const int wr = w >> 1, wc = w & 1;
  const int lg = lane >> 4, li = lane & 15;

  // prologue: features f32 -> fp8 into Bs[0], swizzled on 16B chunks
  #pragma unroll
  for (int i = 0; i < 8; ++i) {
    int q = i * 256 + t;              // 2048 chunks of 8 elements
    int r = q >> 4, c8 = q & 15;      // row, 8-elem chunk (16 per row)
    const float* src = features + (size_t)(row0 + r) * DIM + c8 * 8;
    float4 v0 = *(const float4*)src;
    float4 v1 = *(const float4*)(src + 4);
    int lo = __builtin_amdgcn_cvt_pk_fp8_f32(v0.x, v0.y, 0, false);
    lo     = __builtin_amdgcn_cvt_pk_fp8_f32(v0.z, v0.w, lo, true);
    int hi = __builtin_amdgcn_cvt_pk_fp8_f32(v1.x, v1.y, 0, false);
    hi     = __builtin_amdgcn_cvt_pk_fp8_f32(v1.z, v1.w, hi, true);
    int2 pk; pk.x = lo; pk.y = hi;
    *(int2*)&Bs[0][r * 128 + (((c8 >> 1) ^ (r & 7)) * 16) + (c8 & 1) * 8] = pk;
  }
  __syncthreads();

  // A fragments: per m, 32 bytes (k = lg*32 .. +31) = chunks lg*2, lg*2+1
  int32x8 a8[4];
  #pragma unroll
  for (int m = 0; m < 4; ++m) {
    int r = wr * 64 + m * 16 + li;
    int32x4 lo = *(const int32x4*)&Bs[0][r * 128 + (((lg * 2) ^ (r & 7)) * 16)];
    int32x4 hi = *(const int32x4*)&Bs[0][r * 128 + (((lg * 2 + 1) ^ (r & 7)) * 16)];
    a8[m][0] = lo[0]; a8[m][1] = lo[1]; a8[m][2] = lo[2]; a8[m][3] = lo[3];
    a8[m][4] = hi[0]; a8[m][5] = hi[1]; a8[m][6] = hi[2]; a8[m][7] = hi[3];
  }
  __syncthreads();

  float bv[4][4];
  int   bc[4][4];
  #pragma unroll
  for (int m = 0; m < 4; ++m)
    #pragma unroll
    for (int j = 0; j < 4; ++j) { bv[m][j] = -3.0e38f; bc[m][j] = 0; }
  const f32x4 zero4 = {0.f, 0.f, 0.f, 0.f};
  const int SCALE1 = 0x7F7F7F7F;  // e8m0 bias 127 = x1.0 per 32-elem block

  stage_f8(cf8, tile0 * 128, w, lane, Bs[0]);
  __syncthreads();

  for (int tt = 0; tt < NT; ++tt) {
    if (tt + 1 < NT)
      stage_f8(cf8, (tile0 + tt + 1) * 128, w, lane, Bs[(tt + 1) & 1]);
    const unsigned char* cur = Bs[tt & 1];

    // n-split in halves: bounds register pressure (~110 VGPR)
    #pragma unroll
    for (int h = 0; h < 2; ++h) {
      int32x8 b8[2];
      #pragma unroll
      for (int n2 = 0; n2 < 2; ++n2) {
        int cc = wc * 64 + (h * 2 + n2) * 16 + li;
        int32x4 lo = *(const int32x4*)&cur[cc * 128 + (((lg * 2) ^ (cc & 7)) * 16)];
        int32x4 hi = *(const int32x4*)&cur[cc * 128 + (((lg * 2 + 1) ^ (cc & 7)) * 16)];
        b8[n2][0] = lo[0]; b8[n2][1] = lo[1]; b8[n2][2] = lo[2]; b8[n2][3] = lo[3];
        b8[n2][4] = hi[0]; b8[n2][5] = hi[1]; b8[n2][6] = hi[2]; b8[n2][7] = hi[3];
      }
      #pragma unroll
      for (int m = 0; m < 4; ++m)
        #pragma unroll
        for (int n2 = 0; n2 < 2; ++n2) {
          f32x4 acc = __builtin_amdgcn_mfma_scale_f32_16x16x128_f8f6f4(
              a8[m], b8[n2], zero4, 0, 0, 0, SCALE1, 0, SCALE1);
          const int cbase = (tile0 + tt) * 128 + wc * 64 + (h * 2 + n2) * 16 + li;
          #pragma unroll
          for (int j = 0; j < 4; ++j) {
            float v = acc[j];
            if (v > bv[m][j]) { bv[m][j] = v; bc[m][j] = cbase; }  // strict >: smallest col wins
          }
        }
    }
    __syncthreads();
  }

  // strip-end: cross-lane (val,col) reduce, one atomic per row
  #pragma unroll
  for (int m = 0; m < 4; ++m)
    #pragma unroll
    for (int j = 0; j < 4; ++j) {
      float v = bv[m][j];
      int   c = bc[m][j];
      #pragma unroll
      for (int msk = 1; msk < 16; msk <<= 1) {
        float ov = __shfl_xor(v, msk, 64);
        int   oc = __shfl_xor(c, msk, 64);
        if (ov > v || (ov == v && oc < c)) { v = ov; c = oc; }
      }
      if (li == 0) atomicMax(&gpacked[row0 + wr * 64 + m * 16 + lg * 4 + j], packMax(v, c));
    }
}

__global__ __launch_bounds__(256) void finalize_rows(const unsigned long long* __restrict__ gpacked,
                                                     const float* __restrict__ centsum,
                                                     float* __restrict__ jsum) {
  __shared__ float sdata[4];
  int b = blockIdx.x * 256 + threadIdx.x;
  unsigned long long pk = gpacked[b];
  unsigned int key = (unsigned int)(pk >> 32);
  unsigned int col = 0xFFFFFFFFu - (unsigned int)(pk & 0xFFFFFFFFu);
  unsigned int bits = (key & 0x80000000u) ? (key & 0x7FFFFFFFu) : ~key;
  float mraw = __uint_as_float(bits);          // raw max dot (unscaled)
  float p = exp2f(mraw * SCL);                 // = exp(max dot / T)
  float J = logf(p) - logf(p + centsum[col]);  // BALANCE = 1.0
  #pragma unroll
  for (int msk = 1; msk < 64; msk <<= 1) J += __shfl_xor(J, msk, 64);
  int lane = threadIdx.x & 63, wv = threadIdx.x >> 6;
  if (lane == 0) sdata[wv] = J;
  __syncthreads();
  if (threadIdx.x == 0) atomicAdd(jsum, sdata[0] + sdata[1] + sdata[2] + sdata[3]);
}

__global__ void write_out(const float* __restrict__ jsum, float* __restrict__ out) {
  out[0] = -(jsum[0] / (float)B_ROWS);
}

extern "C" void kernel_launch(void* const* d_in, const int* in_sizes, int n_in,
                              void* d_out, int out_size, void* d_ws, size_t ws_size,
                              hipStream_t stream) {
  const float* features  = (const float*)d_in[0];
  const float* centroids = (const float*)d_in[1];
  float* out = (float*)d_out;

  // ws: cbf_u[S*D] u16 (3.28MB) | cf8[S*D] u8 (1.64MB) | centsum[S] f32 | gpacked[B] u64 | jsum (~5.1 MB)
  unsigned short* cbf_u = (unsigned short*)d_ws;
  unsigned char*  cf8   = (unsigned char*)(cbf_u + (size_t)S_ROWS * DIM);
  float* centsum = (float*)(cf8 + (size_t)S_ROWS * DIM);
  unsigned long long* gpacked = (unsigned long long*)(centsum + S_ROWS);
  float* jsum = (float*)(gpacked + B_ROWS);

  prep<<<dim3(3264), dim3(256), 0, stream>>>(centroids, cbf_u, cf8, centsum, gpacked, jsum);
  // symmetric S x S: 5 chunks x 100 strips = 500 blocks, ~10 tiles each (5050 total)
  sym_mfma<<<dim3(5, NBLK), dim3(256), 0, stream>>>(cbf_u, centsum);
  // B x S argmax: 4 chunks x 128 row-blocks = 512 blocks, 25 tiles each (MX-fp8)
  argmax_mfma<<<dim3(4, B_ROWS / 128), dim3(256), 0, stream>>>(features, cf8, gpacked);
  finalize_rows<<<dim3(B_ROWS / 256), dim3(256), 0, stream>>>(gpacked, centsum, jsum);
  write_out<<<dim3(1), dim3(1), 0, stream>>>(jsum, out);
}

// Round 10
// 100.945 us; speedup vs baseline: 1.1874x; 1.0255x over previous
//
#include <hip/hip_runtime.h>

#define B_ROWS 16384
#define S_ROWS 12800
#define DIM    128
#define NBLK   100          // S_ROWS / 128

static constexpr float SQS = 4.5398160f;  // sqrt(log2(e)/0.07); SQS*SQS = SCL

typedef __attribute__((ext_vector_type(4))) float f32x4;
typedef __attribute__((ext_vector_type(4))) int   int32x4;
typedef __attribute__((ext_vector_type(8))) int   int32x8;

// Sortable packing: larger float -> larger key; ties -> smaller col wins (matches jnp.argmax).
__device__ __forceinline__ unsigned long long packMax(float v, int col) {
  unsigned int b = __float_as_uint(v);
  unsigned int key = (b & 0x80000000u) ? ~b : (b | 0x80000000u);
  return ((unsigned long long)key << 32) | (unsigned long long)(0xFFFFFFFFu - (unsigned int)col);
}

// async global->LDS, 16B per lane, wave-uniform LDS base (HW adds lane*16)
__device__ __forceinline__ void gld16(const void* g, void* l) {
  __builtin_amdgcn_global_load_lds(
      (const __attribute__((address_space(1))) unsigned int*)g,
      (__attribute__((address_space(3))) unsigned int*)l,
      16, 0, 0);
}

// normalize centroids -> fp8 e4m3 of c * sqrt(SCL); init accumulators
__global__ __launch_bounds__(256) void prep(const float* __restrict__ cent,
                                            unsigned char* __restrict__ cf8,
                                            float* __restrict__ centsum,
                                            unsigned long long* __restrict__ gpacked,
                                            float* __restrict__ jsum) {
  int bid = blockIdx.x;
  if (bid >= 3200) {  // 64 init blocks
    int i = (bid - 3200) * 256 + threadIdx.x;
    if (i < S_ROWS) centsum[i] = 0.f;
    if (i < B_ROWS) gpacked[i] = 0ull;
    if (i == 0) jsum[0] = 0.f;
    return;
  }
  int row  = bid * 4 + (threadIdx.x >> 6);
  int lane = threadIdx.x & 63;
  float2 v = ((const float2*)(cent + (size_t)row * DIM))[lane];
  float ss = v.x * v.x + v.y * v.y;
  #pragma unroll
  for (int m = 32; m; m >>= 1) ss += __shfl_xor(ss, m, 64);
  float inv = SQS / fmaxf(sqrtf(ss), 1e-12f);
  int pk = __builtin_amdgcn_cvt_pk_fp8_f32(v.x * inv, v.y * inv, 0, false);
  ((unsigned short*)(cf8 + (size_t)row * 128))[lane] = (unsigned short)pk;
}

// stage one 128-row x 128-K fp8 tile (16 KB); wave w stages rows [w*32, w*32+32)
__device__ __forceinline__ void stage_f8(const unsigned char* __restrict__ src, int base,
                                         int w, int lane, unsigned char* dst) {
  #pragma unroll
  for (int i = 0; i < 4; ++i) {
    int rb = w * 32 + i * 8;
    int r  = rb + (lane >> 3);
    int ch = (lane & 7) ^ (r & 7);
    gld16(src + (size_t)(base + r) * 128 + ch * 16, dst + rb * 128);
  }
}

// read one 16x128 fp8 MFMA operand fragment (row r, k = lg*32..+31)
__device__ __forceinline__ int32x8 frag_f8(const unsigned char* __restrict__ lds, int r, int lg) {
  int32x4 lo = *(const int32x4*)&lds[r * 128 + (((lg * 2) ^ (r & 7)) * 16)];
  int32x4 hi = *(const int32x4*)&lds[r * 128 + (((lg * 2 + 1) ^ (r & 7)) * 16)];
  int32x8 o;
  o[0] = lo[0]; o[1] = lo[1]; o[2] = lo[2]; o[3] = lo[3];
  o[4] = hi[0]; o[5] = hi[1]; o[6] = hi[2]; o[7] = hi[3];
  return o;
}

// ---- symmetric S x S, MX-fp8 (A=B=cf8, dots pre-scaled by SCL).
// Block (chunk c of 8, strip bi): col tiles k in [start,end) of cyclic fold
// bj=(bi+k)%100, k=0..50 (k=50 only for bi<50). Off-diag tiles feed rowsums
// AND colsums (mirror).
__global__ __launch_bounds__(256, 3) void sym_mfma(const unsigned char* __restrict__ cf8,
                                                   float* __restrict__ centsum) {
  __shared__ unsigned char Bs[2][128 * 128];  // 2 x 16 KB

  const int bi   = blockIdx.y;          // strip 0..99
  const int c    = blockIdx.x;          // chunk 0..7
  const int row0 = bi * 128;
  int start = (51 * c) >> 3;            // 0,6,12,19,25,31,38,44
  int end   = (51 * (c + 1)) >> 3;      // ... 51
  if (bi >= 50 && end > 50) end = 50;   // k=50 owned by bi<50 only
  const int nt = end - start;

  const int t    = threadIdx.x;
  const int w    = t >> 6;
  const int lane = t & 63;
  const int wr = w >> 1, wc = w & 1;
  const int lg = lane >> 4, li = lane & 15;

  // ---- prologue: A tile into Bs[0]; fragments -> registers ----
  stage_f8(cf8, row0, w, lane, Bs[0]);
  asm volatile("s_waitcnt vmcnt(0)" ::: "memory");
  __syncthreads();

  int32x8 a8[4];
  #pragma unroll
  for (int m = 0; m < 4; ++m)
    a8[m] = frag_f8(Bs[0], wr * 64 + m * 16 + li, lg);
  __syncthreads();  // A reads done before Bs[0] is reused

  float rs[4][4];
  #pragma unroll
  for (int m = 0; m < 4; ++m)
    #pragma unroll
    for (int j = 0; j < 4; ++j) rs[m][j] = 0.f;
  const f32x4 zero4 = {0.f, 0.f, 0.f, 0.f};
  const int SCALE1 = 0x7F7F7F7F;  // e8m0 1.0 per 32-elem block

  {
    int bj = bi + start; if (bj >= NBLK) bj -= NBLK;
    stage_f8(cf8, bj * 128, w, lane, Bs[0]);
  }
  __syncthreads();

  for (int ii = 0; ii < nt; ++ii) {
    const int k = start + ii;
    if (ii + 1 < nt) {
      int bj2 = bi + k + 1; if (bj2 >= NBLK) bj2 -= NBLK;
      stage_f8(cf8, bj2 * 128, w, lane, Bs[(ii + 1) & 1]);
    }
    int bj = bi + k; if (bj >= NBLK) bj -= NBLK;
    const int colbase = bj * 128;
    const unsigned char* cur = Bs[ii & 1];

    float cs[4] = {0.f, 0.f, 0.f, 0.f};
    #pragma unroll
    for (int h = 0; h < 2; ++h) {
      int32x8 b8[2];
      #pragma unroll
      for (int n2 = 0; n2 < 2; ++n2)
        b8[n2] = frag_f8(cur, wc * 64 + (h * 2 + n2) * 16 + li, lg);
      #pragma unroll
      for (int m = 0; m < 4; ++m)
        #pragma unroll
        for (int n2 = 0; n2 < 2; ++n2) {
          f32x4 acc = __builtin_amdgcn_mfma_scale_f32_16x16x128_f8f6f4(
              a8[m], b8[n2], zero4, 0, 0, 0, SCALE1, 0, SCALE1);
          #pragma unroll
          for (int j = 0; j < 4; ++j) {
            float e = exp2f(acc[j]);      // dot already SCL-scaled
            rs[m][j] += e;
            cs[h * 2 + n2] += e;
          }
        }
    }

    if (k != 0) {  // mirror contribution: centsum[col] += colsum (uniform branch)
      #pragma unroll
      for (int n = 0; n < 4; ++n) {
        cs[n] += __shfl_xor(cs[n], 16, 64);
        cs[n] += __shfl_xor(cs[n], 32, 64);
      }
      if (lg == 0) {
        #pragma unroll
        for (int n = 0; n < 4; ++n)
          atomicAdd(&centsum[colbase + wc * 64 + n * 16 + li], cs[n]);
      }
    }
    __syncthreads();  // prefetch landed + all waves done with cur
  }

  #pragma unroll
  for (int m = 0; m < 4; ++m)
    #pragma unroll
    for (int j = 0; j < 4; ++j) {
      float s = rs[m][j];
      #pragma unroll
      for (int msk = 1; msk < 16; msk <<= 1) s += __shfl_xor(s, msk, 64);
      if (li == 0) atomicAdd(&centsum[row0 + wr * 64 + m * 16 + lg * 4 + j], s);
    }
}

// ---- B x S argmax, MX-fp8. A=features*sqrt(SCL) (f32->fp8 in LDS), B=cf8.
// 8 col-chunks (NT=13/12) x 128 row-blocks = 1024 blocks -> 4 blocks/CU.
__global__ __launch_bounds__(256, 4) void argmax_mfma(const float* __restrict__ features,
                                                      const unsigned char* __restrict__ cf8,
                                                      unsigned long long* __restrict__ gpacked) {
  __shared__ unsigned char Bs[2][128 * 128];  // 2 x 16 KB

  const int row0  = blockIdx.y * 128;
  const int c     = blockIdx.x;                         // 0..7
  const int tile0 = (c < 4) ? 13 * c : 52 + 12 * (c - 4);
  const int nt    = (c < 4) ? 13 : 12;

  const int t    = threadIdx.x;
  const int w    = t >> 6;
  const int lane = t & 63;
  const int wr = w >> 1, wc = w & 1;
  const int lg = lane >> 4, li = lane & 15;

  // prologue: features f32 -> fp8 (scaled by SQS) into Bs[0], swizzled 16B chunks
  #pragma unroll
  for (int i = 0; i < 8; ++i) {
    int q = i * 256 + t;              // 2048 chunks of 8 elements
    int r = q >> 4, c8 = q & 15;
    const float* src = features + (size_t)(row0 + r) * DIM + c8 * 8;
    float4 v0 = *(const float4*)src;
    float4 v1 = *(const float4*)(src + 4);
    int lo = __builtin_amdgcn_cvt_pk_fp8_f32(v0.x * SQS, v0.y * SQS, 0, false);
    lo     = __builtin_amdgcn_cvt_pk_fp8_f32(v0.z * SQS, v0.w * SQS, lo, true);
    int hi = __builtin_amdgcn_cvt_pk_fp8_f32(v1.x * SQS, v1.y * SQS, 0, false);
    hi     = __builtin_amdgcn_cvt_pk_fp8_f32(v1.z * SQS, v1.w * SQS, hi, true);
    int2 pk; pk.x = lo; pk.y = hi;
    *(int2*)&Bs[0][r * 128 + (((c8 >> 1) ^ (r & 7)) * 16) + (c8 & 1) * 8] = pk;
  }
  __syncthreads();

  int32x8 a8[4];
  #pragma unroll
  for (int m = 0; m < 4; ++m)
    a8[m] = frag_f8(Bs[0], wr * 64 + m * 16 + li, lg);
  __syncthreads();

  float bv[4][4];
  int   bc[4][4];
  #pragma unroll
  for (int m = 0; m < 4; ++m)
    #pragma unroll
    for (int j = 0; j < 4; ++j) { bv[m][j] = -3.0e38f; bc[m][j] = 0; }
  const f32x4 zero4 = {0.f, 0.f, 0.f, 0.f};
  const int SCALE1 = 0x7F7F7F7F;

  stage_f8(cf8, tile0 * 128, w, lane, Bs[0]);
  __syncthreads();

  for (int tt = 0; tt < nt; ++tt) {
    if (tt + 1 < nt)
      stage_f8(cf8, (tile0 + tt + 1) * 128, w, lane, Bs[(tt + 1) & 1]);
    const unsigned char* cur = Bs[tt & 1];

    #pragma unroll
    for (int h = 0; h < 2; ++h) {
      int32x8 b8[2];
      #pragma unroll
      for (int n2 = 0; n2 < 2; ++n2)
        b8[n2] = frag_f8(cur, wc * 64 + (h * 2 + n2) * 16 + li, lg);
      #pragma unroll
      for (int m = 0; m < 4; ++m)
        #pragma unroll
        for (int n2 = 0; n2 < 2; ++n2) {
          f32x4 acc = __builtin_amdgcn_mfma_scale_f32_16x16x128_f8f6f4(
              a8[m], b8[n2], zero4, 0, 0, 0, SCALE1, 0, SCALE1);
          const int cbase = (tile0 + tt) * 128 + wc * 64 + (h * 2 + n2) * 16 + li;
          #pragma unroll
          for (int j = 0; j < 4; ++j) {
            float v = acc[j];
            if (v > bv[m][j]) { bv[m][j] = v; bc[m][j] = cbase; }  // strict >: smallest col wins
          }
        }
    }
    __syncthreads();
  }

  // strip-end: cross-lane (val,col) reduce, one atomic per row
  #pragma unroll
  for (int m = 0; m < 4; ++m)
    #pragma unroll
    for (int j = 0; j < 4; ++j) {
      float v = bv[m][j];
      int   cc = bc[m][j];
      #pragma unroll
      for (int msk = 1; msk < 16; msk <<= 1) {
        float ov = __shfl_xor(v, msk, 64);
        int   oc = __shfl_xor(cc, msk, 64);
        if (ov > v || (ov == v && oc < cc)) { v = ov; cc = oc; }
      }
      if (li == 0) atomicMax(&gpacked[row0 + wr * 64 + m * 16 + lg * 4 + j], packMax(v, cc));
    }
}

__global__ __launch_bounds__(256) void finalize_rows(const unsigned long long* __restrict__ gpacked,
                                                     const float* __restrict__ centsum,
                                                     float* __restrict__ jsum) {
  __shared__ float sdata[4];
  int b = blockIdx.x * 256 + threadIdx.x;
  unsigned long long pk = gpacked[b];
  unsigned int key = (unsigned int)(pk >> 32);
  unsigned int col = 0xFFFFFFFFu - (unsigned int)(pk & 0xFFFFFFFFu);
  unsigned int bits = (key & 0x80000000u) ? (key & 0x7FFFFFFFu) : ~key;
  float msc = __uint_as_float(bits);           // max dot, already SCL-scaled
  float p = exp2f(msc);                        // = exp(max dot / T)
  float J = logf(p) - logf(p + centsum[col]);  // BALANCE = 1.0
  #pragma unroll
  for (int msk = 1; msk < 64; msk <<= 1) J += __shfl_xor(J, msk, 64);
  int lane = threadIdx.x & 63, wv = threadIdx.x >> 6;
  if (lane == 0) sdata[wv] = J;
  __syncthreads();
  if (threadIdx.x == 0) atomicAdd(jsum, sdata[0] + sdata[1] + sdata[2] + sdata[3]);
}

__global__ void write_out(const float* __restrict__ jsum, float* __restrict__ out) {
  out[0] = -(jsum[0] / (float)B_ROWS);
}

extern "C" void kernel_launch(void* const* d_in, const int* in_sizes, int n_in,
                              void* d_out, int out_size, void* d_ws, size_t ws_size,
                              hipStream_t stream) {
  const float* features  = (const float*)d_in[0];
  const float* centroids = (const float*)d_in[1];
  float* out = (float*)d_out;

  // ws: cf8[S*D] u8 (1.64MB) | centsum[S] f32 | gpacked[B] u64 | jsum f32  (~1.8 MB)
  unsigned char* cf8 = (unsigned char*)d_ws;
  float* centsum = (float*)(cf8 + (size_t)S_ROWS * DIM);
  unsigned long long* gpacked = (unsigned long long*)(centsum + S_ROWS);
  float* jsum = (float*)(gpacked + B_ROWS);

  prep<<<dim3(3264), dim3(256), 0, stream>>>(centroids, cf8, centsum, gpacked, jsum);
  // symmetric S x S: 8 chunks x 100 strips = 800 blocks (5050 tiles)
  sym_mfma<<<dim3(8, NBLK), dim3(256), 0, stream>>>(cf8, centsum);
  // B x S argmax: 8 chunks x 128 row-blocks = 1024 blocks
  argmax_mfma<<<dim3(8, B_ROWS / 128), dim3(256), 0, stream>>>(features, cf8, gpacked);
  finalize_rows<<<dim3(B_ROWS / 256), dim3(256), 0, stream>>>(gpacked, centsum, jsum);
  write_out<<<dim3(1), dim3(1), 0, stream>>>(jsum, out);
}